// Round 6
// baseline (79.042 us; speedup 1.0000x reference)
//
#include <hip/hip_runtime.h>
#include <math.h>

#define NN 512

typedef __attribute__((ext_vector_type(8))) short bf16x8;
typedef __attribute__((ext_vector_type(4))) float f32x4;
typedef __attribute__((ext_vector_type(4))) unsigned int u32x4;

__device__ inline unsigned short f2bf(float f) {
    unsigned u = __builtin_bit_cast(unsigned, f);
    u += 0x7fffu + ((u >> 16) & 1u);   // round-to-nearest-even
    return (unsigned short)(u >> 16);
}
__device__ inline float bf2f(unsigned short h) {
    unsigned u = ((unsigned)h) << 16;
    return __builtin_bit_cast(float, u);
}
__device__ inline unsigned cvtpk_bf16(float lo, float hi) {
    unsigned r;
    asm("v_cvt_pk_bf16_f32 %0, %1, %2" : "=v"(r) : "v"(lo), "v"(hi));
    return r;
}

// Parity-split DCT matrices: Ce[kk][n] = C[2kk][n], Co[kk][n] = C[2kk+1][n], n<256.
__global__ __launch_bounds__(256) void fill_dct_half(unsigned short* __restrict__ Ce,
                                                     unsigned short* __restrict__ Co) {
    int idx = blockIdx.x * 256 + threadIdx.x;     // 0..131071
    int par = idx >> 16;
    int kk = (idx >> 8) & 255;
    int n = idx & 255;
    int k = 2 * kk + par;
    int m = ((2 * n + 1) * k) & 2047;
    float ang = (float)m * 3.0679615757712823e-3f;   // * pi/1024
    float s = (k == 0) ? 0.04419417382415922f : 0.0625f;
    unsigned short v = f2bf(s * cosf(ang));
    if (par) Co[kk * 256 + n] = v; else Ce[kk * 256 + n] = v;
}

#define GLB(p) ((const __attribute__((address_space(1))) unsigned int*)(const void*)(p))
#define LDS(p) ((__attribute__((address_space(3))) unsigned int*)(p))

// R13: 512 threads / 8 waves of 4x4 (64x64) over a 128x256 block tile.
//  - Convoy theory: every pipe <=50% busy; the K-step barrier convoy length
//    tracks ds_read volume. 4x4 wave tile: 8 frag reads / 16 MFMA
//    (0.5 KB/MFMA) vs R12's 6/8 (0.75) -> 33% fewer LDS reads per output.
//  - 256-wide k-tile = one full parity (Ce or Co, 256 rows, grow0=0):
//    bx-split gone, X re-read 2x not 4x, 768 blocks (8/image).
//  - LDS: G 3x16KB + reg 2x8KB = 64KB; p1 epilogue (256x132 transpose)
//    unions into staging behind a barrier -> 67.6KB -> 2 blocks/CU.
//  - Regs at (512,4) cap 128: acc 64 + depth-1 raw 16 + frags 32 + addr
//    ~= 112-120. Depth-1 proven equal (R7==R10). Spill gate: FETCH/WRITE.
//  - Schedule: cw(kt+1) [implicit drain, 1-step-old loads], stage(kt+2)x2,
//    lr(kt+2), compute, lgkmcnt(0), vmcnt(6/4) counted, kt=6 drains 0,
//    1 barrier/step.
// PASS 1: T'[k][r] = sum_{n<256} (x[r][n] +- x[r][511-n]) * Ce/Co[k'][n]
//         par=0: even k (+, Ce); par=1: odd k (-, Co). k' = 0..255.
// PASS 2: Out[q][k] = sum_{r<256} Ce/Co[q'][r] * (T'[k][r] +- T'[k][511-r])
//         par=0: even q (+, Ce); par=1: odd q (-, Co). q' = 0..255.
template <int PASS>
__global__ __launch_bounds__(512, 4) void gemm_dct(const void* __restrict__ Ap,
                                                   const unsigned short* __restrict__ Ce,
                                                   const unsigned short* __restrict__ Cop,
                                                   void* __restrict__ Outp,
                                                   size_t strideIn, size_t strideOut) {
    const int nwg = (int)gridDim.x;
    const int cpx = nwg >> 3;
    const int bid = (int)blockIdx.x;
    const int nid = (bid & 7) * cpx + (bid >> 3);   // bijective XCD swizzle (nwg%8==0)
    const int par = nid & 1;          // parity: 0 -> Ce/+, 1 -> Co/-
    const int bq = (nid >> 1) & 3;    // p1: r-block (by); p2: k-block (bk)
    const int bz = nid >> 3;

    // p1: Rs [0,8192) + Gs [8192,32768) shorts; epilogue 256x132=33792 unions over all.
    // p2: Gs [0,24576) + Rs [24576,32768).
    __shared__ unsigned short sm[PASS == 1 ? 33792 : 32768];
    unsigned short* const Rs = (PASS == 1) ? sm : sm + 24576;   // reg side, 2 x 4096
    unsigned short* const Gs = (PASS == 1) ? sm + 8192 : sm;    // gload side, 3 x 8192

    const int t = threadIdx.x;
    const int lane = t & 63;
    const int wave = t >> 6;                 // 0..7
    const int lr = lane & 15;
    const int kgx = ((lane >> 4) * 8) ^ (((lr >> 1) & 3) << 3);
    // A-side rows: p1 = reg side (128 rows, 2 wave-strips); p2 = gload (256, 4 strips)
    const int AW = (PASS == 1) ? (wave >> 2) : (wave >> 1);
    const int BW = (PASS == 1) ? (wave & 3) : (wave & 1);

    // gload staging: 256x32 bf16/step; 2 calls (rows +0,+128); linear dest = lane*16B
    const int srow = t >> 2;                 // 0..127
    const int sslot = t & 3;
    const int scol = (sslot ^ ((srow >> 1) & 3)) * 8;   // pre-swizzled source octet

    // reg staging: 128x32 bf16/step; t -> (row t>>2, quarter t&3), one u32x4
    const int frow = t >> 2;
    const int fq = t & 3;
    const int fslot = (fq ^ ((frow >> 1) & 3)) * 8;

    const float* Xf = nullptr;
    const unsigned short* Tp = nullptr;
    const unsigned short* const Gmat = par ? Cop : Ce;
    const float sgnf = par ? -1.0f : 1.0f;
    int row0 = 0, col0 = 0;
    if constexpr (PASS == 1) {
        Xf = (const float*)Ap + (size_t)bz * strideIn;
        row0 = bq * 128;                      // r-rows of this tile
    } else {
        Tp = (const unsigned short*)Ap + (size_t)bz * strideIn;
        col0 = bq * 128;                      // k-cols of this tile
    }

    f32x4 acc[4][4] = {};

    // depth-1 raw tile (fwd + mirror), single set
    f32x4 rf[2], rm[2];      // pass 1 (fp32)
    bf16x8 gf, gm;           // pass 2 (bf16)

    auto stageG = [&](int buf, int k0) {
        __builtin_amdgcn_global_load_lds(GLB(Gmat + (size_t)srow * 256 + k0 + scol),
                                         LDS(&Gs[buf * 8192 + srow * 32 + sslot * 8]), 16, 0, 0);
        __builtin_amdgcn_global_load_lds(GLB(Gmat + (size_t)(128 + srow) * 256 + k0 + scol),
                                         LDS(&Gs[buf * 8192 + (128 + srow) * 32 + sslot * 8]), 16, 0, 0);
    };
    auto doLR = [&](int k0) {
        if constexpr (PASS == 1) {
            const float* bfp = Xf + (size_t)(row0 + frow) * NN + k0 + fq * 8;
            const float* bmp = Xf + (size_t)(row0 + frow) * NN + (504 - k0 - fq * 8);
            rf[0] = *reinterpret_cast<const f32x4*>(bfp);
            rf[1] = *reinterpret_cast<const f32x4*>(bfp + 4);
            rm[0] = *reinterpret_cast<const f32x4*>(bmp);
            rm[1] = *reinterpret_cast<const f32x4*>(bmp + 4);
        } else {
            const unsigned short* bfp = Tp + (size_t)(col0 + frow) * NN + k0 + fq * 8;
            const unsigned short* bmp = Tp + (size_t)(col0 + frow) * NN + (504 - k0 - fq * 8);
            gf = *reinterpret_cast<const bf16x8*>(bfp);
            gm = *reinterpret_cast<const bf16x8*>(bmp);
        }
    };
    auto doCW = [&](int s) {
        const int buf = s & 1;
        unsigned p[4];
        if constexpr (PASS == 1) {
#pragma unroll
            for (int q = 0; q < 4; ++q) {
                const int j0 = 2 * q, j1 = 2 * q + 1;
                const int r0 = 7 - j0, r1 = 7 - j1;
                float s0 = fmaf(sgnf, rm[r0 >> 2][r0 & 3], rf[j0 >> 2][j0 & 3]);
                float s1 = fmaf(sgnf, rm[r1 >> 2][r1 & 3], rf[j1 >> 2][j1 & 3]);
                p[q] = cvtpk_bf16(s0, s1);
            }
        } else {
#pragma unroll
            for (int q = 0; q < 4; ++q) {
                const int j0 = 2 * q, j1 = 2 * q + 1;
                float a0 = bf2f((unsigned short)gf[j0]);
                float a1 = bf2f((unsigned short)gf[j1]);
                float b0 = bf2f((unsigned short)gm[7 - j0]);
                float b1 = bf2f((unsigned short)gm[7 - j1]);
                p[q] = cvtpk_bf16(fmaf(sgnf, b0, a0), fmaf(sgnf, b1, a1));
            }
        }
        u32x4 w = {p[0], p[1], p[2], p[3]};
        *reinterpret_cast<u32x4*>(&Rs[buf * 4096 + frow * 32 + fslot]) = w;
    };
    auto compute = [&](int kt) {
        const int rofs = (kt & 1) * 4096;
        const int gofs = (kt % 3) * 8192;
        const unsigned short* const Aside = (PASS == 1) ? Rs : Gs;
        const unsigned short* const Bside = (PASS == 1) ? Gs : Rs;
        const int aofs = (PASS == 1) ? rofs : gofs;
        const int bofs = (PASS == 1) ? gofs : rofs;
        bf16x8 a[4], b[4];
#pragma unroll
        for (int mi = 0; mi < 4; ++mi)
            a[mi] = *reinterpret_cast<const bf16x8*>(
                &Aside[aofs + (AW * 64 + mi * 16 + lr) * 32 + kgx]);
#pragma unroll
        for (int ni = 0; ni < 4; ++ni)
            b[ni] = *reinterpret_cast<const bf16x8*>(
                &Bside[bofs + (BW * 64 + ni * 16 + lr) * 32 + kgx]);
        __builtin_amdgcn_s_setprio(1);
#pragma unroll
        for (int mi = 0; mi < 4; ++mi)
#pragma unroll
            for (int ni = 0; ni < 4; ++ni)
                acc[mi][ni] = __builtin_amdgcn_mfma_f32_16x16x32_bf16(a[mi], b[ni],
                                                                      acc[mi][ni], 0, 0, 0);
        __builtin_amdgcn_s_setprio(0);
    };

    // ---- prologue: step0 staged+written; raw step1 in flight ----
    stageG(0, 0);
    doLR(0);
    asm volatile("" ::: "memory");      // pin FIFO: step0 VMEM first
    doCW(0);                            // implicit per-wave drain of raw(0)+stage(0)
    stageG(1, 32);
    asm volatile("" ::: "memory");      // pin: stage(1) before raw(1)
    doLR(32);
    asm volatile("s_waitcnt lgkmcnt(0)" ::: "memory");
    if constexpr (PASS == 1) asm volatile("s_waitcnt vmcnt(6)" ::: "memory");
    else                     asm volatile("s_waitcnt vmcnt(4)" ::: "memory");
    __builtin_amdgcn_s_barrier();

    // ---- 8 K-steps, fully unrolled; 1 barrier per step ----
#pragma unroll
    for (int kt = 0; kt < 8; ++kt) {
        if (kt + 1 <= 7) doCW(kt + 1);     // consumes raw loaded at kt-1 (implicit drain)
        if (kt + 2 <= 7) {
            stageG((kt + 2) % 3, (kt + 2) * 32);
            asm volatile("" ::: "memory"); // pin: stage(kt+2) before raw(kt+2)
            doLR((kt + 2) * 32);
        }
        compute(kt);
        asm volatile("s_waitcnt lgkmcnt(0)" ::: "memory");
        if (kt <= 5) {
            // outstanding: stage(kt+2)[2] + lr(kt+2)[4 or 2] -> keep in flight
            if constexpr (PASS == 1) asm volatile("s_waitcnt vmcnt(6)" ::: "memory");
            else                     asm volatile("s_waitcnt vmcnt(4)" ::: "memory");
        } else if (kt == 6) {
            asm volatile("s_waitcnt vmcnt(0)" ::: "memory");   // stage(7) visible for compute(7)
        }
        if (kt < 7) __builtin_amdgcn_s_barrier();
    }

    // ---- epilogue. C/D frag: row = (lane>>4)*4 + reg, col = lane&15 ----
    if constexpr (PASS == 1) {
        // Transposed store with parity row interleave, staged via LDS (unions
        // with staging; barrier first since other waves may still hold reads).
        unsigned short* T = (unsigned short*)Outp + (size_t)bz * strideOut;
        __builtin_amdgcn_s_barrier();
#pragma unroll
        for (int mi = 0; mi < 4; ++mi)
#pragma unroll
            for (int ni = 0; ni < 4; ++ni) {
                int gr = AW * 64 + mi * 16 + (lane >> 4) * 4;   // local r (0..127)
                int gc = BW * 64 + ni * 16 + lr;                // local k' (0..255)
                ushort4 v;
                v.x = f2bf(acc[mi][ni][0]);
                v.y = f2bf(acc[mi][ni][1]);
                v.z = f2bf(acc[mi][ni][2]);
                v.w = f2bf(acc[mi][ni][3]);
                *reinterpret_cast<ushort4*>(&sm[gc * 132 + gr]) = v;
            }
        asm volatile("s_waitcnt lgkmcnt(0)" ::: "memory");
        __builtin_amdgcn_s_barrier();
#pragma unroll
        for (int it = 0; it < 8; ++it) {
            int gcr = it * 32 + (t >> 4);                       // local k' (0..255)
            int physRow = 2 * gcr + par;                        // natural k
            int cb = (t & 15) * 8;
            u32x4 d = *reinterpret_cast<const u32x4*>(&sm[gcr * 132 + cb]);
            *reinterpret_cast<u32x4*>(&T[(size_t)physRow * NN + row0 + cb]) = d;
        }
    } else {
        float* O = (float*)Outp + (size_t)bz * strideOut;
#pragma unroll
        for (int mi = 0; mi < 4; ++mi)
#pragma unroll
            for (int ni = 0; ni < 4; ++ni) {
                int gc = col0 + BW * 64 + ni * 16 + lr;         // natural k col
#pragma unroll
                for (int rr = 0; rr < 4; ++rr) {
                    int qp = AW * 64 + mi * 16 + (lane >> 4) * 4 + rr;  // local q'
                    int q = 2 * qp + par;                       // natural q row
                    O[(size_t)q * NN + gc] = acc[mi][ni][rr];
                }
            }
    }
}

extern "C" void kernel_launch(void* const* d_in, const int* in_sizes, int n_in,
                              void* d_out, int out_size, void* d_ws, size_t ws_size,
                              hipStream_t stream) {
    const float* x = (const float*)d_in[0];
    float* out = (float*)d_out;

    const int imgs = in_sizes[0] / (NN * NN);            // 96
    const size_t imgElems = (size_t)NN * NN;             // 262144
    const size_t imgB16 = imgElems * 2;                  // 512 KB

    unsigned short* Ce = (unsigned short*)d_ws;          // 128 KB
    unsigned short* Co = Ce + 65536;                     // 128 KB
    unsigned short* Tb = Co + 65536;                     // T' buffers

    long long budget = (long long)ws_size - 262144;
    int maxchunk = (int)(budget / (long long)imgB16);
    if (maxchunk < 1) maxchunk = 1;
    if (maxchunk > imgs) maxchunk = imgs;

    hipLaunchKernelGGL(fill_dct_half, dim3(512), dim3(256), 0, stream, Ce, Co);

    for (int i0 = 0; i0 < imgs; i0 += maxchunk) {
        int c = imgs - i0 < maxchunk ? imgs - i0 : maxchunk;
        hipLaunchKernelGGL((gemm_dct<1>), dim3(8 * c), dim3(512), 0, stream,
                           x + (size_t)i0 * imgElems, Ce, Co, Tb, imgElems, imgElems);
        hipLaunchKernelGGL((gemm_dct<2>), dim3(8 * c), dim3(512), 0, stream,
                           Tb, Ce, Co, out + (size_t)i0 * imgElems, imgElems, imgElems);
    }
}